// Round 7
// baseline (1025.784 us; speedup 1.0000x reference)
//
#include <hip/hip_runtime.h>

#define NN   100000
#define EE   1600000
#define HIDF 128
#define OUTF 64
#define KSEL 32

static __device__ __forceinline__ unsigned int sortable_key(float f) {
    unsigned int u = __float_as_uint(f);
    return (u & 0x80000000u) ? ~u : (u | 0x80000000u);
}

// ---------------- degree histogram ----------------
__global__ __launch_bounds__(256) void hist_kernel(const int* __restrict__ src,
                                                   const int* __restrict__ dst,
                                                   int* __restrict__ cnt_out,
                                                   int* __restrict__ cnt_in, int e) {
    int i = blockIdx.x * 256 + threadIdx.x;
    if (i < e) {
        atomicAdd(&cnt_out[src[i]], 1);
        atomicAdd(&cnt_in[dst[i]], 1);
    }
}

// ---------------- prefix scan (3 kernels) ----------------
__global__ __launch_bounds__(256) void scan_block(const int* __restrict__ cnt,
                                                  int* __restrict__ incl,
                                                  int* __restrict__ bsums, int n) {
    __shared__ int s[256];
    int t = threadIdx.x;
    int i = blockIdx.x * 256 + t;
    int v = (i < n) ? cnt[i] : 0;
    s[t] = v;
    __syncthreads();
    for (int off = 1; off < 256; off <<= 1) {
        int x = (t >= off) ? s[t - off] : 0;
        __syncthreads();
        s[t] += x;
        __syncthreads();
    }
    if (i < n) incl[i] = s[t];
    if (t == 255) bsums[blockIdx.x] = s[255];
}

__global__ __launch_bounds__(512) void scan_sums(const int* __restrict__ bsums,
                                                 int* __restrict__ boff, int nb) {
    __shared__ int s[512];
    int t = threadIdx.x;
    int v = (t < nb) ? bsums[t] : 0;
    s[t] = v;
    __syncthreads();
    for (int off = 1; off < 512; off <<= 1) {
        int x = (t >= off) ? s[t - off] : 0;
        __syncthreads();
        s[t] += x;
        __syncthreads();
    }
    boff[t] = s[t] - v;  // exclusive
}

__global__ __launch_bounds__(256) void finalize_offsets(const int* __restrict__ incl,
                                                        const int* __restrict__ boff,
                                                        const int* __restrict__ cnt_in,
                                                        const int* __restrict__ cnt_out,
                                                        int* __restrict__ row_off,
                                                        int* __restrict__ cursor,
                                                        float* __restrict__ dvo,
                                                        float* __restrict__ dvi, int n) {
    int i = blockIdx.x * 256 + threadIdx.x;
    if (i < n) {
        int ci = cnt_in[i];
        int val = incl[i] + boff[i >> 8];
        row_off[i + 1] = val;
        cursor[i] = val - ci;
        if (i == 0) row_off[0] = 0;
        dvo[i] = rsqrtf((float)max(cnt_out[i], 1));
        dvi[i] = rsqrtf((float)max(ci, 1));
    }
}

__global__ __launch_bounds__(256) void csr_fill(const int* __restrict__ src,
                                                const int* __restrict__ dst,
                                                int* __restrict__ cursor,
                                                int* __restrict__ csr, int e) {
    int i = blockIdx.x * 256 + threadIdx.x;
    if (i < e) {
        int d = dst[i];
        int pos = atomicAdd(&cursor[d], 1);
        csr[pos] = src[i];
    }
}

// ---------------- GEMM [n,128] x [128,128] + bias + ReLU (LDS-free) ----------------
// W streamed via per-lane coalesced global loads (L1/L2-resident, all waves in
// lockstep); A via 32-lane-uniform broadcast loads. No LDS, no barriers ->
// occupancy limited only by VGPR.
__global__ __launch_bounds__(256, 4) void gemm_relu(const float* __restrict__ A,
                                                    const float* __restrict__ W,
                                                    const float* __restrict__ bias,
                                                    float* __restrict__ out, int n) {
    const int tid = threadIdx.x;
    const int rbase = blockIdx.x * 64;
    const int cc = tid & 31;
    const int r0 = (tid >> 5) * 8;
    const bool full = (rbase + 64) <= n;
    const float* a_base = A + (size_t)(rbase + r0) * 128;
    const float* w_base = W + cc * 4;
    float acc[8][4];
#pragma unroll
    for (int i = 0; i < 8; ++i) { acc[i][0] = 0.f; acc[i][1] = 0.f; acc[i][2] = 0.f; acc[i][3] = 0.f; }

    if (full) {
#pragma unroll 2
        for (int kq = 0; kq < 32; ++kq) {
            int k = kq * 4;
            float4 w0 = *(const float4*)(w_base + (size_t)(k + 0) * 128);
            float4 w1 = *(const float4*)(w_base + (size_t)(k + 1) * 128);
            float4 w2 = *(const float4*)(w_base + (size_t)(k + 2) * 128);
            float4 w3 = *(const float4*)(w_base + (size_t)(k + 3) * 128);
#pragma unroll
            for (int i = 0; i < 8; ++i) {
                float4 a = *(const float4*)(a_base + (size_t)i * 128 + k);
                acc[i][0] += a.x * w0.x + a.y * w1.x + a.z * w2.x + a.w * w3.x;
                acc[i][1] += a.x * w0.y + a.y * w1.y + a.z * w2.y + a.w * w3.y;
                acc[i][2] += a.x * w0.z + a.y * w1.z + a.z * w2.z + a.w * w3.z;
                acc[i][3] += a.x * w0.w + a.y * w1.w + a.z * w2.w + a.w * w3.w;
            }
        }
    } else {
#pragma unroll 2
        for (int kq = 0; kq < 32; ++kq) {
            int k = kq * 4;
            float4 w0 = *(const float4*)(w_base + (size_t)(k + 0) * 128);
            float4 w1 = *(const float4*)(w_base + (size_t)(k + 1) * 128);
            float4 w2 = *(const float4*)(w_base + (size_t)(k + 2) * 128);
            float4 w3 = *(const float4*)(w_base + (size_t)(k + 3) * 128);
#pragma unroll
            for (int i = 0; i < 8; ++i) {
                float4 a = make_float4(0.f, 0.f, 0.f, 0.f);
                if (rbase + r0 + i < n) a = *(const float4*)(a_base + (size_t)i * 128 + k);
                acc[i][0] += a.x * w0.x + a.y * w1.x + a.z * w2.x + a.w * w3.x;
                acc[i][1] += a.x * w0.y + a.y * w1.y + a.z * w2.y + a.w * w3.y;
                acc[i][2] += a.x * w0.z + a.y * w1.z + a.z * w2.z + a.w * w3.z;
                acc[i][3] += a.x * w0.w + a.y * w1.w + a.z * w2.w + a.w * w3.w;
            }
        }
    }
    float4 b4 = *(const float4*)(bias + cc * 4);
#pragma unroll
    for (int i = 0; i < 8; ++i) {
        int gr = rbase + r0 + i;
        if (gr < n) {
            float4 o = make_float4(fmaxf(acc[i][0] + b4.x, 0.f), fmaxf(acc[i][1] + b4.y, 0.f),
                                   fmaxf(acc[i][2] + b4.z, 0.f), fmaxf(acc[i][3] + b4.w, 0.f));
            *(float4*)(out + (size_t)gr * 128 + cc * 4) = o;
        }
    }
}

// ---------------- GEMM + bias + MaxK(top-32) fused in-register (LDS-free) ----------------
__global__ __launch_bounds__(256, 4) void gemm_maxk(const float* __restrict__ A,
                                                    const float* __restrict__ W,
                                                    const float* __restrict__ bias,
                                                    const float* __restrict__ dvout,
                                                    float* __restrict__ svals, int n) {
    const int tid = threadIdx.x;
    const int rbase = blockIdx.x * 64;
    const int cc = tid & 31;
    const int r0 = (tid >> 5) * 8;
    const float* a_base = A + (size_t)(rbase + r0) * 128;   // hbuf is row-padded
    const float* w_base = W + cc * 4;
    float acc[8][4];
#pragma unroll
    for (int i = 0; i < 8; ++i) { acc[i][0] = 0.f; acc[i][1] = 0.f; acc[i][2] = 0.f; acc[i][3] = 0.f; }

#pragma unroll 2
    for (int kq = 0; kq < 32; ++kq) {
        int k = kq * 4;
        float4 w0 = *(const float4*)(w_base + (size_t)(k + 0) * 128);
        float4 w1 = *(const float4*)(w_base + (size_t)(k + 1) * 128);
        float4 w2 = *(const float4*)(w_base + (size_t)(k + 2) * 128);
        float4 w3 = *(const float4*)(w_base + (size_t)(k + 3) * 128);
#pragma unroll
        for (int i = 0; i < 8; ++i) {
            float4 a = *(const float4*)(a_base + (size_t)i * 128 + k);
            acc[i][0] += a.x * w0.x + a.y * w1.x + a.z * w2.x + a.w * w3.x;
            acc[i][1] += a.x * w0.y + a.y * w1.y + a.z * w2.y + a.w * w3.y;
            acc[i][2] += a.x * w0.z + a.y * w1.z + a.z * w2.z + a.w * w3.z;
            acc[i][3] += a.x * w0.w + a.y * w1.w + a.z * w2.w + a.w * w3.w;
        }
    }

    // ---- fused MaxK select, 8-way ILP radix chain ----
    const int lane = tid & 63;
    const int wvi = tid >> 6;
    const bool up = lane >= 32;
    const unsigned lt32 = (1u << (lane & 31)) - 1u;
    float4 b4 = *(const float4*)(bias + cc * 4);

    unsigned keys[8][4];
#pragma unroll
    for (int i = 0; i < 8; ++i) {
        acc[i][0] += b4.x; acc[i][1] += b4.y; acc[i][2] += b4.z; acc[i][3] += b4.w;
        keys[i][0] = sortable_key(acc[i][0]);
        keys[i][1] = sortable_key(acc[i][1]);
        keys[i][2] = sortable_key(acc[i][2]);
        keys[i][3] = sortable_key(acc[i][3]);
    }
    unsigned prefL[8], prefU[8];
#pragma unroll
    for (int i = 0; i < 8; ++i) { prefL[i] = 0u; prefU[i] = 0u; }

    for (int bit = 31; bit >= 8; --bit) {
        unsigned msk = 1u << bit;
#pragma unroll
        for (int i = 0; i < 8; ++i) {
            unsigned cL = prefL[i] | msk;
            unsigned cU = prefU[i] | msk;
            unsigned myc = up ? cU : cL;
            unsigned long long b0 = __ballot(keys[i][0] >= myc);
            unsigned long long b1 = __ballot(keys[i][1] >= myc);
            unsigned long long b2 = __ballot(keys[i][2] >= myc);
            unsigned long long b3 = __ballot(keys[i][3] >= myc);
            int cntL = __popc((unsigned)b0) + __popc((unsigned)b1) +
                       __popc((unsigned)b2) + __popc((unsigned)b3);
            int cntU = __popc((unsigned)(b0 >> 32)) + __popc((unsigned)(b1 >> 32)) +
                       __popc((unsigned)(b2 >> 32)) + __popc((unsigned)(b3 >> 32));
            prefL[i] = (cntL >= KSEL) ? cL : prefL[i];
            prefU[i] = (cntU >= KSEL) ? cU : prefU[i];
        }
    }

#pragma unroll 1
    for (int i = 0; i < 8; ++i) {
        int row = rbase + 16 * wvi + i + (up ? 8 : 0);
        unsigned myp = up ? prefU[i] : prefL[i];
        unsigned kb0 = keys[i][0] & 0xFFFFFF00u, kb1 = keys[i][1] & 0xFFFFFF00u;
        unsigned kb2 = keys[i][2] & 0xFFFFFF00u, kb3 = keys[i][3] & 0xFFFFFF00u;
        unsigned long long g0 = __ballot(kb0 > myp), g1 = __ballot(kb1 > myp);
        unsigned long long g2 = __ballot(kb2 > myp), g3 = __ballot(kb3 > myp);
        unsigned long long e0 = __ballot(kb0 == myp), e1 = __ballot(kb1 == myp);
        unsigned long long e2 = __ballot(kb2 == myp), e3 = __ballot(kb3 == myp);
        unsigned gh0 = up ? (unsigned)(g0 >> 32) : (unsigned)g0;
        unsigned gh1 = up ? (unsigned)(g1 >> 32) : (unsigned)g1;
        unsigned gh2 = up ? (unsigned)(g2 >> 32) : (unsigned)g2;
        unsigned gh3 = up ? (unsigned)(g3 >> 32) : (unsigned)g3;
        unsigned eh0 = up ? (unsigned)(e0 >> 32) : (unsigned)e0;
        unsigned eh1 = up ? (unsigned)(e1 >> 32) : (unsigned)e1;
        unsigned eh2 = up ? (unsigned)(e2 >> 32) : (unsigned)e2;
        unsigned eh3 = up ? (unsigned)(e3 >> 32) : (unsigned)e3;
        int m = __popc(gh0) + __popc(gh1) + __popc(gh2) + __popc(gh3);
        int need = KSEL - m;
        int gpos = __popc(gh0 & lt32) + __popc(gh1 & lt32) + __popc(gh2 & lt32) + __popc(gh3 & lt32);
        int epos = __popc(eh0 & lt32) + __popc(eh1 & lt32) + __popc(eh2 & lt32) + __popc(eh3 & lt32);
        bool ok = row < n;
        float ds = dvout[row];
        size_t base = (size_t)row * 32;
        unsigned cbit = (unsigned)(lane & 31);
        // j = 0
        {
            int slot = -1;
            if (kb0 > myp) slot = gpos;
            else if (kb0 == myp && epos < need) slot = m + epos;
            if (slot >= 0 && ok) {
                unsigned u = (__float_as_uint(acc[i][0] * ds) & 0xFFFFFF80u) | (unsigned)(cc * 4 + 0);
                svals[base + slot] = __uint_as_float(u);
            }
            gpos += (gh0 >> cbit) & 1u;
            epos += (eh0 >> cbit) & 1u;
        }
        // j = 1
        {
            int slot = -1;
            if (kb1 > myp) slot = gpos;
            else if (kb1 == myp && epos < need) slot = m + epos;
            if (slot >= 0 && ok) {
                unsigned u = (__float_as_uint(acc[i][1] * ds) & 0xFFFFFF80u) | (unsigned)(cc * 4 + 1);
                svals[base + slot] = __uint_as_float(u);
            }
            gpos += (gh1 >> cbit) & 1u;
            epos += (eh1 >> cbit) & 1u;
        }
        // j = 2
        {
            int slot = -1;
            if (kb2 > myp) slot = gpos;
            else if (kb2 == myp && epos < need) slot = m + epos;
            if (slot >= 0 && ok) {
                unsigned u = (__float_as_uint(acc[i][2] * ds) & 0xFFFFFF80u) | (unsigned)(cc * 4 + 2);
                svals[base + slot] = __uint_as_float(u);
            }
            gpos += (gh2 >> cbit) & 1u;
            epos += (eh2 >> cbit) & 1u;
        }
        // j = 3
        {
            int slot = -1;
            if (kb3 > myp) slot = gpos;
            else if (kb3 == myp && epos < need) slot = m + epos;
            if (slot >= 0 && ok) {
                unsigned u = (__float_as_uint(acc[i][3] * ds) & 0xFFFFFF80u) | (unsigned)(cc * 4 + 3);
                svals[base + slot] = __uint_as_float(u);
            }
        }
    }
}

// ---------------- CSR aggregation: atomic-free ----------------
__global__ __launch_bounds__(256) void agg_kernel(const float* __restrict__ svals,
                                                  const int* __restrict__ row_off,
                                                  const int* __restrict__ csr_src,
                                                  const float* __restrict__ dvin,
                                                  const float* __restrict__ bg,
                                                  float* __restrict__ out, int n) {
    __shared__ float acc[4][2][128];  // [wave][slot][feature], wave-private
    const int wv = threadIdx.x >> 6;
    const int lane = threadIdx.x & 63;
    const int sub = lane >> 5;   // which edge slot
    const int j = lane & 31;     // entry within record
    const int node = blockIdx.x * 4 + wv;
    float* base0 = &acc[wv][0][0];
    base0[lane] = 0.f;
    base0[lane + 64] = 0.f;
    base0[lane + 128] = 0.f;
    base0[lane + 192] = 0.f;
    if (node < n) {
        int s0 = row_off[node], s1 = row_off[node + 1];
        float* Ac = &acc[wv][sub][0];
        int e = s0 + sub;
        for (; e + 2 < s1; e += 4) {
            int sA = csr_src[e];
            int sB = csr_src[e + 2];
            float vA = svals[(size_t)sA * 32 + j];
            float vB = svals[(size_t)sB * 32 + j];
            int fA = (int)(__float_as_uint(vA) & 127u);
            Ac[fA] += vA;
            int fB = (int)(__float_as_uint(vB) & 127u);
            Ac[fB] += vB;
        }
        for (; e < s1; e += 2) {
            int sA = csr_src[e];
            float vA = svals[(size_t)sA * 32 + j];
            int fA = (int)(__float_as_uint(vA) & 127u);
            Ac[fA] += vA;
        }
    }
    if (node < n) {
        float dv = dvin[node];
        float r0 = acc[wv][0][lane] + acc[wv][1][lane];
        float r1 = acc[wv][0][lane + 64] + acc[wv][1][lane + 64];
        out[(size_t)node * 128 + lane] = r0 * dv + bg[lane];
        out[(size_t)node * 128 + lane + 64] = r1 * dv + bg[lane + 64];
    }
}

// ---------------- GEMM [n,128] x [128,64] + bias -> d_out (LDS-free) ----------------
__global__ __launch_bounds__(256, 4) void gemm_out64(const float* __restrict__ A,
                                                     const float* __restrict__ W,
                                                     const float* __restrict__ bias,
                                                     float* __restrict__ out, int n) {
    const int tid = threadIdx.x;
    const int rbase = blockIdx.x * 64;
    const int cc = tid & 15;
    const int r0 = (tid >> 4) * 4;
    const float* a_base = A + (size_t)(rbase + r0) * 128;   // hbuf is row-padded
    const float* w_base = W + cc * 4;
    float acc[4][4];
#pragma unroll
    for (int i = 0; i < 4; ++i) { acc[i][0] = 0.f; acc[i][1] = 0.f; acc[i][2] = 0.f; acc[i][3] = 0.f; }

#pragma unroll 2
    for (int kq = 0; kq < 32; ++kq) {
        int k = kq * 4;
        float4 w0 = *(const float4*)(w_base + (size_t)(k + 0) * 64);
        float4 w1 = *(const float4*)(w_base + (size_t)(k + 1) * 64);
        float4 w2 = *(const float4*)(w_base + (size_t)(k + 2) * 64);
        float4 w3 = *(const float4*)(w_base + (size_t)(k + 3) * 64);
#pragma unroll
        for (int i = 0; i < 4; ++i) {
            float4 a = *(const float4*)(a_base + (size_t)i * 128 + k);
            acc[i][0] += a.x * w0.x + a.y * w1.x + a.z * w2.x + a.w * w3.x;
            acc[i][1] += a.x * w0.y + a.y * w1.y + a.z * w2.y + a.w * w3.y;
            acc[i][2] += a.x * w0.z + a.y * w1.z + a.z * w2.z + a.w * w3.z;
            acc[i][3] += a.x * w0.w + a.y * w1.w + a.z * w2.w + a.w * w3.w;
        }
    }
    float4 b4 = *(const float4*)(bias + cc * 4);
#pragma unroll
    for (int i = 0; i < 4; ++i) {
        int gr = rbase + r0 + i;
        if (gr < n) {
            float4 o = make_float4(acc[i][0] + b4.x, acc[i][1] + b4.y,
                                   acc[i][2] + b4.z, acc[i][3] + b4.w);
            *(float4*)(out + (size_t)gr * 64 + cc * 4) = o;
        }
    }
}

extern "C" void kernel_launch(void* const* d_in, const int* in_sizes, int n_in,
                              void* d_out, int out_size, void* d_ws, size_t ws_size,
                              hipStream_t stream) {
    const float* x     = (const float*)d_in[0];
    const int*   src   = (const int*)d_in[1];
    const int*   dst   = (const int*)d_in[2];
    const float* W_in  = (const float*)d_in[3];
    const float* b_in  = (const float*)d_in[4];
    const float* W1    = (const float*)d_in[5];
    const float* b1    = (const float*)d_in[6];
    const float* bg1   = (const float*)d_in[7];
    const float* W2    = (const float*)d_in[8];
    const float* b2    = (const float*)d_in[9];
    const float* bg2   = (const float*)d_in[10];
    const float* W_out = (const float*)d_in[11];
    const float* b_out = (const float*)d_in[12];
    float* out = (float*)d_out;

    char* p = (char*)d_ws;
    auto carve = [&](size_t bytes) {
        char* r = p;
        p += (bytes + 255) & ~(size_t)255;
        return r;
    };
    int*   cnt_out = (int*)carve((size_t)NN * 4);
    int*   cnt_in  = (int*)carve((size_t)NN * 4);
    float* dvout   = (float*)carve((size_t)(NN + 128) * 4);  // padded: gemm_maxk reads OOB rows
    float* dvin    = (float*)carve((size_t)NN * 4);
    int*   incl    = (int*)carve((size_t)NN * 4);
    int*   bsums   = (int*)carve(512 * 4);
    int*   boff    = (int*)carve(512 * 4);
    int*   row_off = (int*)carve((size_t)(NN + 1) * 4);
    int*   cursor  = (int*)carve((size_t)NN * 4);
    int*   csr_src = (int*)carve((size_t)EE * 4);
    float* hbuf    = (float*)carve((size_t)(NN + 128) * HIDF * 4);  // padded rows
    float* svals   = (float*)carve((size_t)NN * KSEL * 4);

    const int gN   = (NN + 255) / 256;   // 391
    const int gE   = (EE + 255) / 256;   // 6250
    const int gT   = (NN + 63) / 64;     // 1563 row tiles
    const int gAgg = (NN + 3) / 4;       // 25000

    hipMemsetAsync(cnt_out, 0, (size_t)NN * 4, stream);
    hipMemsetAsync(cnt_in, 0, (size_t)NN * 4, stream);
    hist_kernel<<<gE, 256, 0, stream>>>(src, dst, cnt_out, cnt_in, EE);
    scan_block<<<gN, 256, 0, stream>>>(cnt_in, incl, bsums, NN);
    scan_sums<<<1, 512, 0, stream>>>(bsums, boff, gN);
    finalize_offsets<<<gN, 256, 0, stream>>>(incl, boff, cnt_in, cnt_out, row_off, cursor,
                                             dvout, dvin, NN);
    csr_fill<<<gE, 256, 0, stream>>>(src, dst, cursor, csr_src, EE);

    gemm_relu<<<gT, 256, 0, stream>>>(x, W_in, b_in, hbuf, NN);

    gemm_maxk<<<gT, 256, 0, stream>>>(hbuf, W1, b1, dvout, svals, NN);
    agg_kernel<<<gAgg, 256, 0, stream>>>(svals, row_off, csr_src, dvin, bg1, hbuf, NN);

    gemm_maxk<<<gT, 256, 0, stream>>>(hbuf, W2, b2, dvout, svals, NN);
    agg_kernel<<<gAgg, 256, 0, stream>>>(svals, row_off, csr_src, dvin, bg2, hbuf, NN);

    gemm_out64<<<gT, 256, 0, stream>>>(hbuf, W_out, b_out, out, NN);
}

// Round 8
// 826.695 us; speedup vs baseline: 1.2408x; 1.2408x over previous
//
#include <hip/hip_runtime.h>

#define NN   100000
#define EE   1600000
#define HIDF 128
#define OUTF 64
#define KSEL 32

static __device__ __forceinline__ unsigned int sortable_key(float f) {
    unsigned int u = __float_as_uint(f);
    return (u & 0x80000000u) ? ~u : (u | 0x80000000u);
}

// ---------------- degree histogram ----------------
__global__ __launch_bounds__(256) void hist_kernel(const int* __restrict__ src,
                                                   const int* __restrict__ dst,
                                                   int* __restrict__ cnt_out,
                                                   int* __restrict__ cnt_in, int e) {
    int i = blockIdx.x * 256 + threadIdx.x;
    if (i < e) {
        atomicAdd(&cnt_out[src[i]], 1);
        atomicAdd(&cnt_in[dst[i]], 1);
    }
}

// ---------------- prefix scan (3 kernels) ----------------
__global__ __launch_bounds__(256) void scan_block(const int* __restrict__ cnt,
                                                  int* __restrict__ incl,
                                                  int* __restrict__ bsums, int n) {
    __shared__ int s[256];
    int t = threadIdx.x;
    int i = blockIdx.x * 256 + t;
    int v = (i < n) ? cnt[i] : 0;
    s[t] = v;
    __syncthreads();
    for (int off = 1; off < 256; off <<= 1) {
        int x = (t >= off) ? s[t - off] : 0;
        __syncthreads();
        s[t] += x;
        __syncthreads();
    }
    if (i < n) incl[i] = s[t];
    if (t == 255) bsums[blockIdx.x] = s[255];
}

__global__ __launch_bounds__(512) void scan_sums(const int* __restrict__ bsums,
                                                 int* __restrict__ boff, int nb) {
    __shared__ int s[512];
    int t = threadIdx.x;
    int v = (t < nb) ? bsums[t] : 0;
    s[t] = v;
    __syncthreads();
    for (int off = 1; off < 512; off <<= 1) {
        int x = (t >= off) ? s[t - off] : 0;
        __syncthreads();
        s[t] += x;
        __syncthreads();
    }
    boff[t] = s[t] - v;  // exclusive
}

__global__ __launch_bounds__(256) void finalize_offsets(const int* __restrict__ incl,
                                                        const int* __restrict__ boff,
                                                        const int* __restrict__ cnt_in,
                                                        const int* __restrict__ cnt_out,
                                                        int* __restrict__ row_off,
                                                        int* __restrict__ cursor,
                                                        float* __restrict__ dvo,
                                                        float* __restrict__ dvi, int n) {
    int i = blockIdx.x * 256 + threadIdx.x;
    if (i < n) {
        int ci = cnt_in[i];
        int val = incl[i] + boff[i >> 8];
        row_off[i + 1] = val;
        cursor[i] = val - ci;
        if (i == 0) row_off[0] = 0;
        dvo[i] = rsqrtf((float)max(cnt_out[i], 1));
        dvi[i] = rsqrtf((float)max(ci, 1));
    }
}

__global__ __launch_bounds__(256) void csr_fill(const int* __restrict__ src,
                                                const int* __restrict__ dst,
                                                int* __restrict__ cursor,
                                                int* __restrict__ csr, int e) {
    int i = blockIdx.x * 256 + threadIdx.x;
    if (i < e) {
        int d = dst[i];
        int pos = atomicAdd(&cursor[d], 1);
        csr[pos] = src[i];
    }
}

// ---------------- GEMM [n,128] x [128,128] + bias + ReLU (A+W in LDS) ----------------
// A-tile (64x128, 32KB) and W-half (64x128, 32KB) both staged in LDS: the
// k-loop touches no global memory (R7 showed global W kills it; R6's residual
// stall was the in-loop broadcast A global loads). 64KB LDS -> 2 blocks/CU.
__global__ __launch_bounds__(256, 2) void gemm_relu(const float* __restrict__ A,
                                                    const float* __restrict__ W,
                                                    const float* __restrict__ bias,
                                                    float* __restrict__ out, int n) {
    __shared__ float As[64][128];
    __shared__ float Ws[64][128];
    const int tid = threadIdx.x;
    const int rbase = blockIdx.x * 64;
    const int cc = tid & 31;
    const int r0 = (tid >> 5) * 8;
    float acc[8][4];
#pragma unroll
    for (int i = 0; i < 8; ++i) { acc[i][0] = 0.f; acc[i][1] = 0.f; acc[i][2] = 0.f; acc[i][3] = 0.f; }

    // stage A (row-guarded: x is not padded)
#pragma unroll
    for (int q = 0; q < 8; ++q) {
        int f = q * 256 + tid;
        int row = rbase + (f >> 5);
        float4 v = make_float4(0.f, 0.f, 0.f, 0.f);
        if (row < n) v = *(const float4*)(A + (size_t)row * 128 + (f & 31) * 4);
        *(float4*)&As[f >> 5][(f & 31) * 4] = v;
    }

    for (int half = 0; half < 2; ++half) {
        const int kb = half * 64;
        if (half) __syncthreads();   // protect Ws overwrite
#pragma unroll
        for (int q = 0; q < 8; ++q) {
            int f = q * 256 + tid;
            *(float4*)&Ws[f >> 5][(f & 31) * 4] = *(const float4*)(W + (size_t)kb * 128 + (size_t)f * 4);
        }
        __syncthreads();
        for (int kq = 0; kq < 16; ++kq) {
            int k = kq * 4;
            float4 w0 = *(float4*)&Ws[k + 0][cc * 4];
            float4 w1 = *(float4*)&Ws[k + 1][cc * 4];
            float4 w2 = *(float4*)&Ws[k + 2][cc * 4];
            float4 w3 = *(float4*)&Ws[k + 3][cc * 4];
#pragma unroll
            for (int i = 0; i < 8; ++i) {
                float4 a = *(float4*)&As[r0 + i][kb + k];
                acc[i][0] += a.x * w0.x + a.y * w1.x + a.z * w2.x + a.w * w3.x;
                acc[i][1] += a.x * w0.y + a.y * w1.y + a.z * w2.y + a.w * w3.y;
                acc[i][2] += a.x * w0.z + a.y * w1.z + a.z * w2.z + a.w * w3.z;
                acc[i][3] += a.x * w0.w + a.y * w1.w + a.z * w2.w + a.w * w3.w;
            }
        }
    }
    float4 b4 = *(const float4*)(bias + cc * 4);
#pragma unroll
    for (int i = 0; i < 8; ++i) {
        int gr = rbase + r0 + i;
        if (gr < n) {
            float4 o = make_float4(fmaxf(acc[i][0] + b4.x, 0.f), fmaxf(acc[i][1] + b4.y, 0.f),
                                   fmaxf(acc[i][2] + b4.z, 0.f), fmaxf(acc[i][3] + b4.w, 0.f));
            *(float4*)(out + (size_t)gr * 128 + cc * 4) = o;
        }
    }
}

// ---------------- GEMM + bias + MaxK(top-32) fused in-register (A+W in LDS) ----------------
__global__ __launch_bounds__(256, 2) void gemm_maxk(const float* __restrict__ A,
                                                    const float* __restrict__ W,
                                                    const float* __restrict__ bias,
                                                    const float* __restrict__ dvout,
                                                    float* __restrict__ svals, int n) {
    __shared__ float As[64][128];
    __shared__ float Ws[64][128];
    const int tid = threadIdx.x;
    const int rbase = blockIdx.x * 64;
    const int cc = tid & 31;
    const int r0 = (tid >> 5) * 8;
    float acc[8][4];
#pragma unroll
    for (int i = 0; i < 8; ++i) { acc[i][0] = 0.f; acc[i][1] = 0.f; acc[i][2] = 0.f; acc[i][3] = 0.f; }

    // stage A (hbuf is row-padded: unguarded)
#pragma unroll
    for (int q = 0; q < 8; ++q) {
        int f = q * 256 + tid;
        *(float4*)&As[f >> 5][(f & 31) * 4] =
            *(const float4*)(A + (size_t)rbase * 128 + (size_t)f * 4);
    }

    for (int half = 0; half < 2; ++half) {
        const int kb = half * 64;
        if (half) __syncthreads();
#pragma unroll
        for (int q = 0; q < 8; ++q) {
            int f = q * 256 + tid;
            *(float4*)&Ws[f >> 5][(f & 31) * 4] = *(const float4*)(W + (size_t)kb * 128 + (size_t)f * 4);
        }
        __syncthreads();
        for (int kq = 0; kq < 16; ++kq) {
            int k = kq * 4;
            float4 w0 = *(float4*)&Ws[k + 0][cc * 4];
            float4 w1 = *(float4*)&Ws[k + 1][cc * 4];
            float4 w2 = *(float4*)&Ws[k + 2][cc * 4];
            float4 w3 = *(float4*)&Ws[k + 3][cc * 4];
#pragma unroll
            for (int i = 0; i < 8; ++i) {
                float4 a = *(float4*)&As[r0 + i][kb + k];
                acc[i][0] += a.x * w0.x + a.y * w1.x + a.z * w2.x + a.w * w3.x;
                acc[i][1] += a.x * w0.y + a.y * w1.y + a.z * w2.y + a.w * w3.y;
                acc[i][2] += a.x * w0.z + a.y * w1.z + a.z * w2.z + a.w * w3.z;
                acc[i][3] += a.x * w0.w + a.y * w1.w + a.z * w2.w + a.w * w3.w;
            }
        }
    }

    // ---- fused MaxK select (unchanged from R6) ----
    const int lane = tid & 63;
    const int wvi = tid >> 6;
    const bool up = lane >= 32;
    const unsigned lt32 = (1u << (lane & 31)) - 1u;
    float4 b4 = *(const float4*)(bias + cc * 4);

    unsigned keys[8][4];
#pragma unroll
    for (int i = 0; i < 8; ++i) {
        acc[i][0] += b4.x; acc[i][1] += b4.y; acc[i][2] += b4.z; acc[i][3] += b4.w;
        keys[i][0] = sortable_key(acc[i][0]);
        keys[i][1] = sortable_key(acc[i][1]);
        keys[i][2] = sortable_key(acc[i][2]);
        keys[i][3] = sortable_key(acc[i][3]);
    }
    unsigned prefL[8], prefU[8];
#pragma unroll
    for (int i = 0; i < 8; ++i) { prefL[i] = 0u; prefU[i] = 0u; }

    for (int bit = 31; bit >= 8; --bit) {
        unsigned msk = 1u << bit;
#pragma unroll
        for (int i = 0; i < 8; ++i) {
            unsigned cL = prefL[i] | msk;
            unsigned cU = prefU[i] | msk;
            unsigned myc = up ? cU : cL;
            unsigned long long b0 = __ballot(keys[i][0] >= myc);
            unsigned long long b1 = __ballot(keys[i][1] >= myc);
            unsigned long long b2 = __ballot(keys[i][2] >= myc);
            unsigned long long b3 = __ballot(keys[i][3] >= myc);
            int cntL = __popc((unsigned)b0) + __popc((unsigned)b1) +
                       __popc((unsigned)b2) + __popc((unsigned)b3);
            int cntU = __popc((unsigned)(b0 >> 32)) + __popc((unsigned)(b1 >> 32)) +
                       __popc((unsigned)(b2 >> 32)) + __popc((unsigned)(b3 >> 32));
            prefL[i] = (cntL >= KSEL) ? cL : prefL[i];
            prefU[i] = (cntU >= KSEL) ? cU : prefU[i];
        }
    }

#pragma unroll 1
    for (int i = 0; i < 8; ++i) {
        int row = rbase + 16 * wvi + i + (up ? 8 : 0);
        unsigned myp = up ? prefU[i] : prefL[i];
        unsigned kb0 = keys[i][0] & 0xFFFFFF00u, kb1 = keys[i][1] & 0xFFFFFF00u;
        unsigned kb2 = keys[i][2] & 0xFFFFFF00u, kb3 = keys[i][3] & 0xFFFFFF00u;
        unsigned long long g0 = __ballot(kb0 > myp), g1 = __ballot(kb1 > myp);
        unsigned long long g2 = __ballot(kb2 > myp), g3 = __ballot(kb3 > myp);
        unsigned long long e0 = __ballot(kb0 == myp), e1 = __ballot(kb1 == myp);
        unsigned long long e2 = __ballot(kb2 == myp), e3 = __ballot(kb3 == myp);
        unsigned gh0 = up ? (unsigned)(g0 >> 32) : (unsigned)g0;
        unsigned gh1 = up ? (unsigned)(g1 >> 32) : (unsigned)g1;
        unsigned gh2 = up ? (unsigned)(g2 >> 32) : (unsigned)g2;
        unsigned gh3 = up ? (unsigned)(g3 >> 32) : (unsigned)g3;
        unsigned eh0 = up ? (unsigned)(e0 >> 32) : (unsigned)e0;
        unsigned eh1 = up ? (unsigned)(e1 >> 32) : (unsigned)e1;
        unsigned eh2 = up ? (unsigned)(e2 >> 32) : (unsigned)e2;
        unsigned eh3 = up ? (unsigned)(e3 >> 32) : (unsigned)e3;
        int m = __popc(gh0) + __popc(gh1) + __popc(gh2) + __popc(gh3);
        int need = KSEL - m;
        int gpos = __popc(gh0 & lt32) + __popc(gh1 & lt32) + __popc(gh2 & lt32) + __popc(gh3 & lt32);
        int epos = __popc(eh0 & lt32) + __popc(eh1 & lt32) + __popc(eh2 & lt32) + __popc(eh3 & lt32);
        bool ok = row < n;
        float ds = dvout[row];
        size_t base = (size_t)row * 32;
        unsigned cbit = (unsigned)(lane & 31);
        // j = 0
        {
            int slot = -1;
            if (kb0 > myp) slot = gpos;
            else if (kb0 == myp && epos < need) slot = m + epos;
            if (slot >= 0 && ok) {
                unsigned u = (__float_as_uint(acc[i][0] * ds) & 0xFFFFFF80u) | (unsigned)(cc * 4 + 0);
                svals[base + slot] = __uint_as_float(u);
            }
            gpos += (gh0 >> cbit) & 1u;
            epos += (eh0 >> cbit) & 1u;
        }
        // j = 1
        {
            int slot = -1;
            if (kb1 > myp) slot = gpos;
            else if (kb1 == myp && epos < need) slot = m + epos;
            if (slot >= 0 && ok) {
                unsigned u = (__float_as_uint(acc[i][1] * ds) & 0xFFFFFF80u) | (unsigned)(cc * 4 + 1);
                svals[base + slot] = __uint_as_float(u);
            }
            gpos += (gh1 >> cbit) & 1u;
            epos += (eh1 >> cbit) & 1u;
        }
        // j = 2
        {
            int slot = -1;
            if (kb2 > myp) slot = gpos;
            else if (kb2 == myp && epos < need) slot = m + epos;
            if (slot >= 0 && ok) {
                unsigned u = (__float_as_uint(acc[i][2] * ds) & 0xFFFFFF80u) | (unsigned)(cc * 4 + 2);
                svals[base + slot] = __uint_as_float(u);
            }
            gpos += (gh2 >> cbit) & 1u;
            epos += (eh2 >> cbit) & 1u;
        }
        // j = 3
        {
            int slot = -1;
            if (kb3 > myp) slot = gpos;
            else if (kb3 == myp && epos < need) slot = m + epos;
            if (slot >= 0 && ok) {
                unsigned u = (__float_as_uint(acc[i][3] * ds) & 0xFFFFFF80u) | (unsigned)(cc * 4 + 3);
                svals[base + slot] = __uint_as_float(u);
            }
        }
    }
}

// ---------------- CSR aggregation: atomic-free ----------------
__global__ __launch_bounds__(256) void agg_kernel(const float* __restrict__ svals,
                                                  const int* __restrict__ row_off,
                                                  const int* __restrict__ csr_src,
                                                  const float* __restrict__ dvin,
                                                  const float* __restrict__ bg,
                                                  float* __restrict__ out, int n) {
    __shared__ float acc[4][2][128];  // [wave][slot][feature], wave-private
    const int wv = threadIdx.x >> 6;
    const int lane = threadIdx.x & 63;
    const int sub = lane >> 5;   // which edge slot
    const int j = lane & 31;     // entry within record
    const int node = blockIdx.x * 4 + wv;
    float* base0 = &acc[wv][0][0];
    base0[lane] = 0.f;
    base0[lane + 64] = 0.f;
    base0[lane + 128] = 0.f;
    base0[lane + 192] = 0.f;
    if (node < n) {
        int s0 = row_off[node], s1 = row_off[node + 1];
        float* Ac = &acc[wv][sub][0];
        int e = s0 + sub;
        for (; e + 2 < s1; e += 4) {
            int sA = csr_src[e];
            int sB = csr_src[e + 2];
            float vA = svals[(size_t)sA * 32 + j];
            float vB = svals[(size_t)sB * 32 + j];
            int fA = (int)(__float_as_uint(vA) & 127u);
            Ac[fA] += vA;
            int fB = (int)(__float_as_uint(vB) & 127u);
            Ac[fB] += vB;
        }
        for (; e < s1; e += 2) {
            int sA = csr_src[e];
            float vA = svals[(size_t)sA * 32 + j];
            int fA = (int)(__float_as_uint(vA) & 127u);
            Ac[fA] += vA;
        }
    }
    if (node < n) {
        float dv = dvin[node];
        float r0 = acc[wv][0][lane] + acc[wv][1][lane];
        float r1 = acc[wv][0][lane + 64] + acc[wv][1][lane + 64];
        out[(size_t)node * 128 + lane] = r0 * dv + bg[lane];
        out[(size_t)node * 128 + lane + 64] = r1 * dv + bg[lane + 64];
    }
}

// ---------------- GEMM [n,128] x [128,64] + bias -> d_out (A+W in LDS) ----------------
__global__ __launch_bounds__(256, 2) void gemm_out64(const float* __restrict__ A,
                                                     const float* __restrict__ W,
                                                     const float* __restrict__ bias,
                                                     float* __restrict__ out, int n) {
    __shared__ float As[64][128];
    __shared__ float Ws[128][64];
    const int tid = threadIdx.x;
    const int rbase = blockIdx.x * 64;
    const int cc = tid & 15;
    const int r0 = (tid >> 4) * 4;
    float acc[4][4];
#pragma unroll
    for (int i = 0; i < 4; ++i) { acc[i][0] = 0.f; acc[i][1] = 0.f; acc[i][2] = 0.f; acc[i][3] = 0.f; }

#pragma unroll
    for (int q = 0; q < 8; ++q) {
        int f = q * 256 + tid;
        *(float4*)&As[f >> 5][(f & 31) * 4] =
            *(const float4*)(A + (size_t)rbase * 128 + (size_t)f * 4);   // hbuf padded
    }
#pragma unroll
    for (int q = 0; q < 8; ++q) {
        int f = q * 256 + tid;
        *(float4*)&Ws[f >> 4][(f & 15) * 4] = *(const float4*)(W + (size_t)f * 4);
    }
    __syncthreads();
    for (int kq = 0; kq < 32; ++kq) {
        int k = kq * 4;
        float4 w0 = *(float4*)&Ws[k + 0][cc * 4];
        float4 w1 = *(float4*)&Ws[k + 1][cc * 4];
        float4 w2 = *(float4*)&Ws[k + 2][cc * 4];
        float4 w3 = *(float4*)&Ws[k + 3][cc * 4];
#pragma unroll
        for (int i = 0; i < 4; ++i) {
            float4 a = *(float4*)&As[r0 + i][k];
            acc[i][0] += a.x * w0.x + a.y * w1.x + a.z * w2.x + a.w * w3.x;
            acc[i][1] += a.x * w0.y + a.y * w1.y + a.z * w2.y + a.w * w3.y;
            acc[i][2] += a.x * w0.z + a.y * w1.z + a.z * w2.z + a.w * w3.z;
            acc[i][3] += a.x * w0.w + a.y * w1.w + a.z * w2.w + a.w * w3.w;
        }
    }
    float4 b4 = *(const float4*)(bias + cc * 4);
#pragma unroll
    for (int i = 0; i < 4; ++i) {
        int gr = rbase + r0 + i;
        if (gr < n) {
            float4 o = make_float4(acc[i][0] + b4.x, acc[i][1] + b4.y,
                                   acc[i][2] + b4.z, acc[i][3] + b4.w);
            *(float4*)(out + (size_t)gr * 64 + cc * 4) = o;
        }
    }
}

extern "C" void kernel_launch(void* const* d_in, const int* in_sizes, int n_in,
                              void* d_out, int out_size, void* d_ws, size_t ws_size,
                              hipStream_t stream) {
    const float* x     = (const float*)d_in[0];
    const int*   src   = (const int*)d_in[1];
    const int*   dst   = (const int*)d_in[2];
    const float* W_in  = (const float*)d_in[3];
    const float* b_in  = (const float*)d_in[4];
    const float* W1    = (const float*)d_in[5];
    const float* b1    = (const float*)d_in[6];
    const float* bg1   = (const float*)d_in[7];
    const float* W2    = (const float*)d_in[8];
    const float* b2    = (const float*)d_in[9];
    const float* bg2   = (const float*)d_in[10];
    const float* W_out = (const float*)d_in[11];
    const float* b_out = (const float*)d_in[12];
    float* out = (float*)d_out;

    char* p = (char*)d_ws;
    auto carve = [&](size_t bytes) {
        char* r = p;
        p += (bytes + 255) & ~(size_t)255;
        return r;
    };
    int*   cnt_out = (int*)carve((size_t)NN * 4);
    int*   cnt_in  = (int*)carve((size_t)NN * 4);
    float* dvout   = (float*)carve((size_t)(NN + 128) * 4);  // padded: gemm_maxk reads OOB rows
    float* dvin    = (float*)carve((size_t)NN * 4);
    int*   incl    = (int*)carve((size_t)NN * 4);
    int*   bsums   = (int*)carve(512 * 4);
    int*   boff    = (int*)carve(512 * 4);
    int*   row_off = (int*)carve((size_t)(NN + 1) * 4);
    int*   cursor  = (int*)carve((size_t)NN * 4);
    int*   csr_src = (int*)carve((size_t)EE * 4);
    float* hbuf    = (float*)carve((size_t)(NN + 128) * HIDF * 4);  // padded rows
    float* svals   = (float*)carve((size_t)NN * KSEL * 4);

    const int gN   = (NN + 255) / 256;   // 391
    const int gE   = (EE + 255) / 256;   // 6250
    const int gT   = (NN + 63) / 64;     // 1563 row tiles
    const int gAgg = (NN + 3) / 4;       // 25000

    hipMemsetAsync(cnt_out, 0, (size_t)NN * 4, stream);
    hipMemsetAsync(cnt_in, 0, (size_t)NN * 4, stream);
    hist_kernel<<<gE, 256, 0, stream>>>(src, dst, cnt_out, cnt_in, EE);
    scan_block<<<gN, 256, 0, stream>>>(cnt_in, incl, bsums, NN);
    scan_sums<<<1, 512, 0, stream>>>(bsums, boff, gN);
    finalize_offsets<<<gN, 256, 0, stream>>>(incl, boff, cnt_in, cnt_out, row_off, cursor,
                                             dvout, dvin, NN);
    csr_fill<<<gE, 256, 0, stream>>>(src, dst, cursor, csr_src, EE);

    gemm_relu<<<gT, 256, 0, stream>>>(x, W_in, b_in, hbuf, NN);

    gemm_maxk<<<gT, 256, 0, stream>>>(hbuf, W1, b1, dvout, svals, NN);
    agg_kernel<<<gAgg, 256, 0, stream>>>(svals, row_off, csr_src, dvin, bg1, hbuf, NN);

    gemm_maxk<<<gT, 256, 0, stream>>>(hbuf, W2, b2, dvout, svals, NN);
    agg_kernel<<<gAgg, 256, 0, stream>>>(svals, row_off, csr_src, dvin, bg2, hbuf, NN);

    gemm_out64<<<gT, 256, 0, stream>>>(hbuf, W_out, b_out, out, NN);
}